// Round 5
// baseline (1532.805 us; speedup 1.0000x reference)
//
#include <hip/hip_runtime.h>
#include <hip/hip_bf16.h>

// Grouped SwiGLU experts: E=8, T=2048, D_IN=2048, D_H=5632. FP32 in/out.
// r9: kill per-step address VALU. LDS sub-rings with COMPILE-TIME offsets:
// A ring-4 @0 (16KB slots), G ring-2 @64K, D ring-2 @96K (128 KB). t-loop
// unrolled x2 so every ds_read is baseVGPR+imm and every stage dest is a
// literal. Staging sources = uniform pointer (SALU-advanced) + loop-invariant
// lane offset. Schedule/accumulation order == r7/r8 (mid-barrier guards the
// same-slot turnaround stages; vmcnt(6)/step).

#define NEXP 8
#define TT   2048
#define DIN  2048
#define DH   5632
#define KP   2080   // padded K pitch (elems) for X / WgT / WdT

using short8 = __attribute__((ext_vector_type(8))) short;   // 8 x bf16
using f32x4  = __attribute__((ext_vector_type(4))) float;   // MFMA acc

static __device__ __forceinline__ unsigned short f2bf(float f) {
    unsigned int i = __float_as_uint(f);
    return (unsigned short)((i + 0x7FFFu + ((i >> 16) & 1u)) >> 16);  // RNE
}
static __device__ __forceinline__ void gld16(const void* g, void* l) {
    __builtin_amdgcn_global_load_lds(
        (const __attribute__((address_space(1))) void*)g,
        (__attribute__((address_space(3))) void*)l, 16, 0, 0);
}

// ---------------------------------------------------------------------------
// Fused G/U GEMM: persistent, 11 tiles of 256x128 per CU, BK=64.
// LDS: A slots {0,16K,32K,48K} (unit 2g+h mod 4), G {64K,64K+16K} (g mod 2),
// D {96K,96K+16K}. Step: read A0,G,D; stage A1(g+1); lgkm; Gtop,Utop;
// read A1; lgkm; Ubot,Gbot; BARRIER; stage A0,G,D(g+2); vmcnt(6); BARRIER.
// ---------------------------------------------------------------------------
#define GU_STEP(TCONST, SA0B, SA1B, SSA1B, SSA0B, GB, DB)                      \
  {                                                                            \
    const int t = (TCONST);                                                    \
    const int g = (i << 5) + t;                                                \
    _Pragma("unroll")                                                          \
    for (int s = 0; s < 4; ++s) {                                              \
      Aq[s][0] = *(const short8*)(ldsc + (SA0B) + ibA[s][0]);                  \
      Aq[s][1] = *(const short8*)(ldsc + (SA0B) + ibA[s][1]);                  \
    }                                                                          \
    _Pragma("unroll")                                                          \
    for (int s = 0; s < 2; ++s) {                                              \
      Gq[s][0] = *(const short8*)(ldsc + (GB) + ibBG[s][0]);                   \
      Gq[s][1] = *(const short8*)(ldsc + (GB) + ibBG[s][1]);                   \
      Dq[s][0] = *(const short8*)(ldsc + (DB) + ibBD[s][0]);                   \
      Dq[s][1] = *(const short8*)(ldsc + (DB) + ibBD[s][1]);                   \
    }                                                                          \
    if (i < 10 || t < 31) {                                                    \
      const unsigned short* ps = Ae128 + ((t + 1) & 31) * 64;                  \
      gld16(ps + loffA0, ldsb + (SSA1B) + wvoff);                              \
      gld16(ps + loffA1, ldsb + (SSA1B) + 8192 + wvoff);                       \
    }                                                                          \
    asm volatile("s_waitcnt lgkmcnt(0)" ::: "memory");                         \
    __builtin_amdgcn_sched_barrier(0);                                         \
    __builtin_amdgcn_s_setprio(1);                                             \
    _Pragma("unroll")                                                          \
    for (int m = 0; m < 4; ++m)                                                \
      _Pragma("unroll")                                                        \
      for (int n = 0; n < 2; ++n) {                                            \
        acc[m][n] = __builtin_amdgcn_mfma_f32_16x16x32_bf16(Aq[m][0], Gq[n][0], acc[m][n], 0, 0, 0); \
        acc[m][n] = __builtin_amdgcn_mfma_f32_16x16x32_bf16(Aq[m][1], Gq[n][1], acc[m][n], 0, 0, 0); \
      }                                                                        \
    _Pragma("unroll")                                                          \
    for (int m = 0; m < 4; ++m)                                                \
      _Pragma("unroll")                                                        \
      for (int n = 0; n < 2; ++n) {                                            \
        acc[m][2 + n] = __builtin_amdgcn_mfma_f32_16x16x32_bf16(Aq[m][0], Dq[n][0], acc[m][2 + n], 0, 0, 0); \
        acc[m][2 + n] = __builtin_amdgcn_mfma_f32_16x16x32_bf16(Aq[m][1], Dq[n][1], acc[m][2 + n], 0, 0, 0); \
      }                                                                        \
    __builtin_amdgcn_s_setprio(0);                                             \
    _Pragma("unroll")                                                          \
    for (int s = 0; s < 4; ++s) {                                              \
      Aq[s][0] = *(const short8*)(ldsc + (SA1B) + ibA[s][0]);                  \
      Aq[s][1] = *(const short8*)(ldsc + (SA1B) + ibA[s][1]);                  \
    }                                                                          \
    asm volatile("s_waitcnt lgkmcnt(0)" ::: "memory");                         \
    __builtin_amdgcn_sched_barrier(0);                                         \
    __builtin_amdgcn_s_setprio(1);                                             \
    _Pragma("unroll")                                                          \
    for (int m = 0; m < 4; ++m)                                                \
      _Pragma("unroll")                                                        \
      for (int n = 0; n < 2; ++n) {                                            \
        acc[4 + m][2 + n] = __builtin_amdgcn_mfma_f32_16x16x32_bf16(Aq[m][0], Dq[n][0], acc[4 + m][2 + n], 0, 0, 0); \
        acc[4 + m][2 + n] = __builtin_amdgcn_mfma_f32_16x16x32_bf16(Aq[m][1], Dq[n][1], acc[4 + m][2 + n], 0, 0, 0); \
      }                                                                        \
    _Pragma("unroll")                                                          \
    for (int m = 0; m < 4; ++m)                                                \
      _Pragma("unroll")                                                        \
      for (int n = 0; n < 2; ++n) {                                            \
        acc[4 + m][n] = __builtin_amdgcn_mfma_f32_16x16x32_bf16(Aq[m][0], Gq[n][0], acc[4 + m][n], 0, 0, 0); \
        acc[4 + m][n] = __builtin_amdgcn_mfma_f32_16x16x32_bf16(Aq[m][1], Gq[n][1], acc[4 + m][n], 0, 0, 0); \
      }                                                                        \
    __builtin_amdgcn_s_setprio(0);                                             \
    asm volatile("s_barrier" ::: "memory");                                    \
    if (i < 10 || t < 30) {                                                    \
      const int k2 = ((t + 2) & 31) * 64;                                      \
      const unsigned short* pa = Ae + k2;                                      \
      gld16(pa + loffA0, ldsb + (SSA0B) + wvoff);                              \
      gld16(pa + loffA1, ldsb + (SSA0B) + 8192 + wvoff);                       \
      const unsigned short* pg = ((t < 30) ? Gc : Gn) + k2;                    \
      gld16(pg + loffW0, ldsb + 65536 + (GB) + wvoff);                         \
      gld16(pg + loffW1, ldsb + 65536 + (GB) + 8192 + wvoff);                  \
      const unsigned short* pd = ((t < 30) ? Dc : Dn) + k2;                    \
      gld16(pd + loffW0, ldsb + 98304 + (DB) + wvoff);                         \
      gld16(pd + loffW1, ldsb + 98304 + (DB) + 8192 + wvoff);                  \
    }                                                                          \
    if (g < 350)       asm volatile("s_waitcnt vmcnt(6)" ::: "memory");        \
    else if (g == 350) asm volatile("s_waitcnt vmcnt(0)" ::: "memory");        \
    asm volatile("s_barrier" ::: "memory");                                    \
  }

__global__ __launch_bounds__(512, 2) void gemm_gu(
    const unsigned short* __restrict__ Xb,   // [E][T][KP] bf16
    const unsigned short* __restrict__ Wgt,  // [E][DH][KP] bf16 (K-major)
    const unsigned short* __restrict__ Wdt,  // [E][DH][KP] bf16
    unsigned short* __restrict__ Hb)         // [E][T][DH] bf16
{
    __shared__ __align__(16) unsigned short lds[65536];  // 128 KB

    const int tid  = threadIdx.x;
    const int wave = tid >> 6, lane = tid & 63;
    const int l15 = lane & 15, l4 = lane >> 4;
    const int wr = wave >> 2, wc = wave & 3;     // 2M x 4N wave grid

    const int bid = blockIdx.x;                  // 256 blocks = 8 XCD * 32 CU
    const int e   = bid & 7;                     // expert == XCD
    const int cu  = bid >> 3;                    // [0,32)
    const int m0  = (cu & 7) * 256;              // constant per CU
    const int nb  = cu >> 3;                     // [0,4): n0(i) = (4i+nb)*128

    const unsigned short* Ae = Xb + (size_t)e * TT * KP + (size_t)m0 * KP;
    const unsigned short* Ae128 = Ae + (size_t)128 * KP;
    unsigned short* He = Hb + (size_t)e * TT * DH;

    // Stage-side lane offsets (loop-invariant).
    const int c0 = tid, c1 = 512 + tid;
    const int cs0 = c0 ^ ((c0 >> 3) & 7), cs1 = c1 ^ ((c1 >> 3) & 7);
    const int row0 = cs0 >> 3, col0 = (cs0 & 7) * 8;
    const int row1 = cs1 >> 3, col1 = (cs1 & 7) * 8;
    const size_t loffA0 = (size_t)row0 * KP + col0;
    const size_t loffA1 = (size_t)row1 * KP + col1;
    const size_t loffW0 = loffA0, loffW1 = loffA1;
    const int wvoff = wave * 1024;

    // Read-side swizzled byte offsets (loop-invariant VGPRs; slot -> imm).
    int ibA[4][2], ibBG[2][2], ibBD[2][2];
#pragma unroll
    for (int s = 0; s < 4; ++s)
#pragma unroll
        for (int ks = 0; ks < 2; ++ks) {
            const int r = wr * 64 + s * 16 + l15;
            ibA[s][ks] = (r * 128 + ks * 64 + l4 * 16) ^ ((r & 7) << 4);
        }
#pragma unroll
    for (int s = 0; s < 2; ++s)
#pragma unroll
        for (int ks = 0; ks < 2; ++ks) {
            const int r = wc * 32 + s * 16 + l15;
            const int b = (r * 128 + ks * 64 + l4 * 16) ^ ((r & 7) << 4);
            ibBG[s][ks] = b + 65536;
            ibBD[s][ks] = b + 98304;
        }

    f32x4 acc[8][4] = {};
    short8 Aq[4][2], Gq[2][2], Dq[2][2];

    char* ldsb = (char*)lds;
    const char* ldsc = (const char*)lds;

    const size_t NSTEP = (size_t)512 * KP;       // 4*128 weight rows per tile
    const unsigned short* Gc = Wgt + (size_t)e * DH * KP + (size_t)(nb * 128) * KP;
    const unsigned short* Dc = Wdt + (size_t)e * DH * KP + (size_t)(nb * 128) * KP;

    // Prologue: units g=0 {A0->0, A1->16K, G->64K, D->96K} first (8 loads),
    // then g=1 {A0->32K, G->64K+16K, D->96K+16K} (6 loads). vmcnt(6) => g0 done.
    gld16(Ae    + loffA0, ldsb + 0 + wvoff);
    gld16(Ae    + loffA1, ldsb + 0 + 8192 + wvoff);
    gld16(Ae128 + loffA0, ldsb + 16384 + wvoff);
    gld16(Ae128 + loffA1, ldsb + 16384 + 8192 + wvoff);
    gld16(Gc    + loffW0, ldsb + 65536 + wvoff);
    gld16(Gc    + loffW1, ldsb + 65536 + 8192 + wvoff);
    gld16(Dc    + loffW0, ldsb + 98304 + wvoff);
    gld16(Dc    + loffW1, ldsb + 98304 + 8192 + wvoff);
    gld16(Ae + 64 + loffA0, ldsb + 32768 + wvoff);
    gld16(Ae + 64 + loffA1, ldsb + 32768 + 8192 + wvoff);
    gld16(Gc + 64 + loffW0, ldsb + 65536 + 16384 + wvoff);
    gld16(Gc + 64 + loffW1, ldsb + 65536 + 16384 + 8192 + wvoff);
    gld16(Dc + 64 + loffW0, ldsb + 98304 + 16384 + wvoff);
    gld16(Dc + 64 + loffW1, ldsb + 98304 + 16384 + 8192 + wvoff);
    asm volatile("s_waitcnt vmcnt(6)" ::: "memory");
    asm volatile("s_barrier" ::: "memory");

    for (int i = 0; i < 11; ++i) {
        const unsigned short* Gn = Gc + NSTEP;
        const unsigned short* Dn = Dc + NSTEP;
        for (int t2 = 0; t2 < 16; ++t2) {
            // even step: A0@0, A1@16K, stA1->48K, stA0->0, G/D slot +0
            GU_STEP(2 * t2,     0,     16384, 49152, 0,     0,     0)
            // odd step:  A0@32K, A1@48K, stA1->16K, stA0->32K, G/D slot +16K
            GU_STEP(2 * t2 + 1, 32768, 49152, 16384, 32768, 16384, 16384)
        }

        // Tile epilogue: H = silu(G)*U. C/D: col=lane&15, row=(lane>>4)*4+j.
        const int n0i = (4 * i + nb) * 128;
#pragma unroll
        for (int fm = 0; fm < 8; ++fm) {
            const int row_b = m0 + (fm >> 2) * 128 + wr * 64 + (fm & 3) * 16 + l4 * 4;
#pragma unroll
            for (int nr = 0; nr < 2; ++nr) {
                const int col = n0i + wc * 32 + nr * 16 + l15;
#pragma unroll
                for (int j = 0; j < 4; ++j) {
                    const float gv = acc[fm][nr][j];
                    const float uv = acc[fm][2 + nr][j];
                    const float h = gv / (1.f + __expf(-gv)) * uv;
                    He[(size_t)(row_b + j) * DH + col] = f2bf(h);
                }
            }
        }
#pragma unroll
        for (int m = 0; m < 8; ++m)
#pragma unroll
            for (int n = 0; n < 4; ++n)
                acc[m][n] = (f32x4){0.f, 0.f, 0.f, 0.f};
        Gc = Gn; Dc = Dn;
    }
}

// ---------------------------------------------------------------------------
// Out-GEMM: persistent, 2 tiles of 256x256 per CU, BK=64. Same sub-ring LDS:
// A ring-4 @0, B0 ring-2 @64K, B1 ring-2 @96K. Same step schedule.
// ---------------------------------------------------------------------------
#define OUT_STEP(TCONST, SA0B, SA1B, SSA1B, SSA0B, B0B, B1B)                   \
  {                                                                            \
    const int t = (TCONST);                                                    \
    const int g = i * 88 + t;                                                  \
    _Pragma("unroll")                                                          \
    for (int s = 0; s < 4; ++s) {                                              \
      Aq[s][0] = *(const short8*)(ldsc + (SA0B) + ibA[s][0]);                  \
      Aq[s][1] = *(const short8*)(ldsc + (SA0B) + ibA[s][1]);                  \
    }                                                                          \
    _Pragma("unroll")                                                          \
    for (int s = 0; s < 2; ++s) {                                              \
      B0q[s][0] = *(const short8*)(ldsc + (B0B) + ibB0[s][0]);                 \
      B0q[s][1] = *(const short8*)(ldsc + (B0B) + ibB0[s][1]);                 \
      B1q[s][0] = *(const short8*)(ldsc + (B1B) + ibB1[s][0]);                 \
      B1q[s][1] = *(const short8*)(ldsc + (B1B) + ibB1[s][1]);                 \
    }                                                                          \
    if (i < 1 || t < 87) {                                                     \
      const int k1 = ((t + 1 >= 88) ? (t + 1 - 88) : (t + 1)) * 64;            \
      const unsigned short* ps = Ae128 + k1;                                   \
      gld16(ps + loffA0, ldsb + (SSA1B) + wvoff);                              \
      gld16(ps + loffA1, ldsb + (SSA1B) + 8192 + wvoff);                       \
    }                                                                          \
    asm volatile("s_waitcnt lgkmcnt(0)" ::: "memory");                         \
    __builtin_amdgcn_sched_barrier(0);                                         \
    __builtin_amdgcn_s_setprio(1);                                             \
    _Pragma("unroll")                                                          \
    for (int m = 0; m < 4; ++m)                                                \
      _Pragma("unroll")                                                        \
      for (int n = 0; n < 2; ++n) {                                            \
        acc[m][n] = __builtin_amdgcn_mfma_f32_16x16x32_bf16(Aq[m][0], B0q[n][0], acc[m][n], 0, 0, 0); \
        acc[m][n] = __builtin_amdgcn_mfma_f32_16x16x32_bf16(Aq[m][1], B0q[n][1], acc[m][n], 0, 0, 0); \
      }                                                                        \
    _Pragma("unroll")                                                          \
    for (int m = 0; m < 4; ++m)                                                \
      _Pragma("unroll")                                                        \
      for (int n = 0; n < 2; ++n) {                                            \
        acc[m][2 + n] = __builtin_amdgcn_mfma_f32_16x16x32_bf16(Aq[m][0], B1q[n][0], acc[m][2 + n], 0, 0, 0); \
        acc[m][2 + n] = __builtin_amdgcn_mfma_f32_16x16x32_bf16(Aq[m][1], B1q[n][1], acc[m][2 + n], 0, 0, 0); \
      }                                                                        \
    __builtin_amdgcn_s_setprio(0);                                             \
    _Pragma("unroll")                                                          \
    for (int s = 0; s < 4; ++s) {                                              \
      Aq[s][0] = *(const short8*)(ldsc + (SA1B) + ibA[s][0]);                  \
      Aq[s][1] = *(const short8*)(ldsc + (SA1B) + ibA[s][1]);                  \
    }                                                                          \
    asm volatile("s_waitcnt lgkmcnt(0)" ::: "memory");                         \
    __builtin_amdgcn_sched_barrier(0);                                         \
    __builtin_amdgcn_s_setprio(1);                                             \
    _Pragma("unroll")                                                          \
    for (int m = 0; m < 4; ++m)                                                \
      _Pragma("unroll")                                                        \
      for (int n = 0; n < 2; ++n) {                                            \
        acc[4 + m][2 + n] = __builtin_amdgcn_mfma_f32_16x16x32_bf16(Aq[m][0], B1q[n][0], acc[4 + m][2 + n], 0, 0, 0); \
        acc[4 + m][2 + n] = __builtin_amdgcn_mfma_f32_16x16x32_bf16(Aq[m][1], B1q[n][1], acc[4 + m][2 + n], 0, 0, 0); \
      }                                                                        \
    _Pragma("unroll")                                                          \
    for (int m = 0; m < 4; ++m)                                                \
      _Pragma("unroll")                                                        \
      for (int n = 0; n < 2; ++n) {                                            \
        acc[4 + m][n] = __builtin_amdgcn_mfma_f32_16x16x32_bf16(Aq[m][0], B0q[n][0], acc[4 + m][n], 0, 0, 0); \
        acc[4 + m][n] = __builtin_amdgcn_mfma_f32_16x16x32_bf16(Aq[m][1], B0q[n][1], acc[4 + m][n], 0, 0, 0); \
      }                                                                        \
    __builtin_amdgcn_s_setprio(0);                                             \
    asm volatile("s_barrier" ::: "memory");                                    \
    if (i < 1 || t < 86) {                                                     \
      const int k2 = ((t + 2 >= 88) ? (t + 2 - 88) : (t + 2)) * 64;            \
      const unsigned short* pa = Ae + k2;                                      \
      gld16(pa + loffA0, ldsb + (SSA0B) + wvoff);                              \
      gld16(pa + loffA1, ldsb + (SSA0B) + 8192 + wvoff);                       \
      const unsigned short* pb = ((t < 86) ? Bc : Bn) + k2;                    \
      gld16(pb + loffB0, ldsb + 65536 + (B0B) + wvoff);                        \
      gld16(pb + loffB1, ldsb + 65536 + (B0B) + 8192 + wvoff);                 \
      const unsigned short* pc = pb + (size_t)128 * DH;                        \
      gld16(pc + loffB0, ldsb + 98304 + (B1B) + wvoff);                        \
      gld16(pc + loffB1, ldsb + 98304 + (B1B) + 8192 + wvoff);                 \
    }                                                                          \
    if (g < 174)       asm volatile("s_waitcnt vmcnt(6)" ::: "memory");        \
    else if (g == 174) asm volatile("s_waitcnt vmcnt(0)" ::: "memory");        \
    asm volatile("s_barrier" ::: "memory");                                    \
  }

__global__ __launch_bounds__(512, 2) void gemm_out(
    const unsigned short* __restrict__ Ab,   // H [E][T][DH] bf16
    const unsigned short* __restrict__ Btb,  // WuT [E][DIN][DH] bf16
    float* __restrict__ Cf)                  // [E][T][DIN] fp32
{
    __shared__ __align__(16) unsigned short lds[65536];  // 128 KB

    const int tid  = threadIdx.x;
    const int wave = tid >> 6, lane = tid & 63;
    const int l15 = lane & 15, l4 = lane >> 4;
    const int wr = wave >> 2, wc = wave & 3;     // 2M x 4N

    const int bid = blockIdx.x;                  // 256
    const int e   = bid & 7;
    const int cu  = bid >> 3;                    // [0,32)
    const int m0  = (cu & 7) * 256;
    const int nb  = cu >> 3;                     // n0(i) = (4i+nb)*256

    const unsigned short* Ae = Ab + (size_t)e * TT * DH + (size_t)m0 * DH;
    const unsigned short* Ae128 = Ae + (size_t)128 * DH;

    const int c0 = tid, c1 = 512 + tid;
    const int cs0 = c0 ^ ((c0 >> 3) & 7), cs1 = c1 ^ ((c1 >> 3) & 7);
    const int row0 = cs0 >> 3, col0 = (cs0 & 7) * 8;
    const int row1 = cs1 >> 3, col1 = (cs1 & 7) * 8;
    const size_t loffA0 = (size_t)row0 * DH + col0;
    const size_t loffA1 = (size_t)row1 * DH + col1;
    const size_t loffB0 = loffA0, loffB1 = loffA1;
    const int wvoff = wave * 1024;

    int ibA[4][2], ibB0[2][2], ibB1[2][2];
#pragma unroll
    for (int s = 0; s < 4; ++s)
#pragma unroll
        for (int ks = 0; ks < 2; ++ks) {
            const int r = wr * 64 + s * 16 + l15;
            ibA[s][ks] = (r * 128 + ks * 64 + l4 * 16) ^ ((r & 7) << 4);
        }
#pragma unroll
    for (int s = 0; s < 2; ++s)
#pragma unroll
        for (int ks = 0; ks < 2; ++ks) {
            const int r = wc * 32 + s * 16 + l15;
            const int b = (r * 128 + ks * 64 + l4 * 16) ^ ((r & 7) << 4);
            ibB0[s][ks] = b + 65536;
            ibB1[s][ks] = b + 98304;
        }

    f32x4 acc[8][4] = {};
    short8 Aq[4][2], B0q[2][2], B1q[2][2];

    char* ldsb = (char*)lds;
    const char* ldsc = (const char*)lds;

    const size_t NSTEP = (size_t)1024 * DH;      // 4*256 B rows per tile
    const unsigned short* Bc = Btb + (size_t)e * DIN * DH + (size_t)(nb * 256) * DH;

    // Prologue: g=0 units first (8 loads), then g=1 (6 loads).
    gld16(Ae    + loffA0, ldsb + 0 + wvoff);
    gld16(Ae    + loffA1, ldsb + 0 + 8192 + wvoff);
    gld16(Ae128 + loffA0, ldsb + 16384 + wvoff);
    gld16(Ae128 + loffA1, ldsb + 16384 + 8192 + wvoff);
    gld16(Bc    + loffB0, ldsb + 65536 + wvoff);
    gld16(Bc    + loffB1, ldsb + 65536 + 8192 + wvoff);
    gld16(Bc + (size_t)128 * DH + loffB0, ldsb + 98304 + wvoff);
    gld16(Bc + (size_t)128 * DH + loffB1, ldsb + 98304 + 8192 + wvoff);
    gld16(Ae + 64 + loffA0, ldsb + 32768 + wvoff);
    gld16(Ae + 64 + loffA1, ldsb + 32768 + 8192 + wvoff);
    gld16(Bc + 64 + loffB0, ldsb + 65536 + 16384 + wvoff);
    gld16(Bc + 64 + loffB1, ldsb + 65536 + 16384 + 8192 + wvoff);
    gld16(Bc + (size_t)128 * DH + 64 + loffB0, ldsb + 98304 + 16384 + wvoff);
    gld16(Bc + (size_t)128 * DH + 64 + loffB1, ldsb + 98304 + 16384 + 8192 + wvoff);
    asm volatile("s_waitcnt vmcnt(6)" ::: "memory");
    asm volatile("s_barrier" ::: "memory");

    for (int i = 0; i < 2; ++i) {
        const unsigned short* Bn = Bc + NSTEP;
        for (int t2 = 0; t2 < 44; ++t2) {
            OUT_STEP(2 * t2,     0,     16384, 49152, 0,     0,     0)
            OUT_STEP(2 * t2 + 1, 32768, 49152, 16384, 32768, 16384, 16384)
        }

        // Tile epilogue: fp32 store, then zero acc.
        const int n0i = (4 * i + nb) * 256;
        float* Ce = Cf + (size_t)e * TT * DIN;
#pragma unroll
        for (int fm = 0; fm < 8; ++fm) {
            const int row_b = (fm >> 2) * 128 + wr * 64 + (fm & 3) * 16 + l4 * 4;
#pragma unroll
            for (int fn = 0; fn < 4; ++fn) {
                const int col = n0i + (fn >> 1) * 128 + wc * 32 + (fn & 1) * 16 + l15;
#pragma unroll
                for (int j = 0; j < 4; ++j)
                    Ce[(size_t)(m0 + row_b + j) * DIN + col] = acc[fm][fn][j];
            }
        }
#pragma unroll
        for (int m = 0; m < 8; ++m)
#pragma unroll
            for (int n = 0; n < 4; ++n)
                acc[m][n] = (f32x4){0.f, 0.f, 0.f, 0.f};
        Bc = Bn;
    }
}

// out[z][C][opitch] (bf16) = convert(in[z][R][C] (f32)). 64x64 tiles.
__global__ __launch_bounds__(256) void transpose_f32_bf16(
    const float* __restrict__ in, unsigned short* __restrict__ out,
    int R, int C, int opitch, size_t ies, size_t oes)
{
    in  += (size_t)blockIdx.z * ies;
    out += (size_t)blockIdx.z * oes;
    __shared__ unsigned short t[64][65];
    const int tid = threadIdx.x;
    const int lr = tid >> 4, lc = (tid & 15) * 4;
    const int r0 = blockIdx.y * 64, c0 = blockIdx.x * 64;
#pragma unroll
    for (int i = 0; i < 4; ++i) {
        const int row = lr + i * 16;
        const float4 v = *(const float4*)(in + (size_t)(r0 + row) * C + c0 + lc);
        t[row][lc + 0] = f2bf(v.x); t[row][lc + 1] = f2bf(v.y);
        t[row][lc + 2] = f2bf(v.z); t[row][lc + 3] = f2bf(v.w);
    }
    __syncthreads();
#pragma unroll
    for (int i = 0; i < 4; ++i) {
        const int crow = lr + i * 16;
        ushort4 wv;
        wv.x = t[lc + 0][crow]; wv.y = t[lc + 1][crow];
        wv.z = t[lc + 2][crow]; wv.w = t[lc + 3][crow];
        *(ushort4*)(out + (size_t)(c0 + crow) * opitch + r0 + lc) = wv;
    }
}

// X [rows][2048] f32 -> [rows][KP] bf16 (row-padded).
__global__ __launch_bounds__(256) void conv_pad_f32_bf16(
    const float* __restrict__ in, unsigned short* __restrict__ out, int n8)
{
    int i = blockIdx.x * 256 + threadIdx.x;
    const int stride = gridDim.x * 256;
    for (; i < n8; i += stride) {
        const int row = i >> 8;                  // 256 chunks of 8 per row
        const int col = (i & 255) * 8;
        const float4 v0 = *(const float4*)(in + (size_t)row * DIN + col);
        const float4 v1 = *(const float4*)(in + (size_t)row * DIN + col + 4);
        ushort4 a, b;
        a.x = f2bf(v0.x); a.y = f2bf(v0.y); a.z = f2bf(v0.z); a.w = f2bf(v0.w);
        b.x = f2bf(v1.x); b.y = f2bf(v1.y); b.z = f2bf(v1.z); b.w = f2bf(v1.w);
        *(ushort4*)(out + (size_t)row * KP + col) = a;
        *(ushort4*)(out + (size_t)row * KP + col + 4) = b;
    }
}

extern "C" void kernel_launch(void* const* d_in, const int* in_sizes, int n_in,
                              void* d_out, int out_size, void* d_ws, size_t ws_size,
                              hipStream_t stream)
{
    const float* x  = (const float*)d_in[0];  // [E,T,DIN]
    const float* wg = (const float*)d_in[1];  // [E,DIN,DH]
    const float* wd = (const float*)d_in[2];  // [E,DIN,DH]
    const float* wu = (const float*)d_in[3];  // [E,DH,DIN]
    float* out = (float*)d_out;               // [E,T,DIN] fp32

    const size_t XSZ = (size_t)TT * KP;       // per-expert X elems (padded)
    const size_t WPSZ = (size_t)DH * KP;      // per-expert padded weight elems
    const size_t WSZ = (size_t)DIN * DH;      // per-expert WuT elems (unpadded)
    unsigned short* xb  = (unsigned short*)d_ws;      // [E] X bf16 padded  68 MB
    unsigned short* wgt = xb  + (size_t)NEXP * XSZ;   // [E] WgT / WuT     188 MB
    unsigned short* wdt = wgt + (size_t)NEXP * WPSZ;  // [E] WdT           188 MB
    unsigned short* hb  = wdt + (size_t)NEXP * WPSZ;  // [E] H             185 MB
    // total ws: ~628 MB

    // X -> bf16 padded rows
    conv_pad_f32_bf16<<<4096, 256, 0, stream>>>(x, xb, NEXP * TT * (DIN / 8));
    // WgT, WdT: [E][DH][KP] K-major padded
    transpose_f32_bf16<<<dim3(DH / 64, DIN / 64, NEXP), 256, 0, stream>>>(
        wg, wgt, DIN, DH, KP, WSZ, WPSZ);
    transpose_f32_bf16<<<dim3(DH / 64, DIN / 64, NEXP), 256, 0, stream>>>(
        wd, wdt, DIN, DH, KP, WSZ, WPSZ);
    // H = silu(X*Wg) * (X*Wd)   [E][T][DH]  — persistent fused dual-acc GEMM
    gemm_gu<<<256, 512, 0, stream>>>(xb, wgt, wdt, hb);
    // WuT: [E][DIN][DH] K-major, stride 5632 non-pow2 (reuse wgt region)
    transpose_f32_bf16<<<dim3(DIN / 64, DH / 64, NEXP), 256, 0, stream>>>(
        wu, wgt, DH, DIN, DH, WSZ, WSZ);
    // Out = H * Wu   [E][T][DIN] fp32  — persistent
    gemm_out<<<256, 512, 0, stream>>>(hb, wgt, out);
}

// Round 6
// 1434.418 us; speedup vs baseline: 1.0686x; 1.0686x over previous
//
#include <hip/hip_runtime.h>
#include <hip/hip_bf16.h>

// Grouped SwiGLU experts: E=8, T=2048, D_IN=2048, D_H=5632. FP32 in/out.
// r10: 32x32x16 MFMA + compiler-scheduled step interior. Same ring-10
// persistent skeleton as r7 (passed): 2 barriers/step, vmcnt(6), stale-slot
// early stages, turnaround stage after a lgkmcnt(0)+schedbar+mid-barrier.
// Small per-subtick frag live-set (28 VGPR vs 96) lets regalloc hoist
// ds_reads under MFMAs -> LDS pipe overlaps MFMA pipe.

#define NEXP 8
#define TT   2048
#define DIN  2048
#define DH   5632
#define KP   2080   // padded K pitch (elems) for X / WgT / WdT

using short8 = __attribute__((ext_vector_type(8))) short;   // 8 x bf16
using f32x16 = __attribute__((ext_vector_type(16))) float;  // 32x32 MFMA acc

static __device__ __forceinline__ unsigned short f2bf(float f) {
    unsigned int i = __float_as_uint(f);
    return (unsigned short)((i + 0x7FFFu + ((i >> 16) & 1u)) >> 16);  // RNE
}
static __device__ __forceinline__ void gld16(const void* g, void* l) {
    __builtin_amdgcn_global_load_lds(
        (const __attribute__((address_space(1))) void*)g,
        (__attribute__((address_space(3))) void*)l, 16, 0, 0);
}

// ---------------------------------------------------------------------------
// Fused G/U GEMM (persistent, ring-10, 32x32x16): 11 tiles of 256x128, BK=64.
// 8 waves 2Mx4N. Per wave: 4 M-tiles (32 rows) x 1 N-tile(32) for G and U.
// Step: early stages {A1(g+1), A0(g+2), G(g+2)}; 24 ds_reads + 32 MFMA
// (compiler-scheduled); lgkm(0)+schedbar; MID BARRIER; stage D(g+2)
// (turnaround into sA0 slot); vmcnt(6); END BARRIER. Slot(g,h)=(4g+h)%10.
// ---------------------------------------------------------------------------
__global__ __launch_bounds__(512, 2) void gemm_gu(
    const unsigned short* __restrict__ Xb,   // [E][T][KP] bf16
    const unsigned short* __restrict__ Wgt,  // [E][DH][KP] bf16 (K-major)
    const unsigned short* __restrict__ Wdt,  // [E][DH][KP] bf16
    unsigned short* __restrict__ Hb)         // [E][T][DH] bf16
{
    __shared__ __align__(16) unsigned short lds[81920];  // 160 KB = 10 x 16 KB

    const int tid  = threadIdx.x;
    const int wave = tid >> 6, lane = tid & 63;
    const int l31 = lane & 31, lh = lane >> 5;
    const int wr = wave >> 2, wc = wave & 3;     // 2M x 4N wave grid

    const int bid = blockIdx.x;                  // 256 blocks = 8 XCD * 32 CU
    const int e   = bid & 7;                     // expert == XCD
    const int cu  = bid >> 3;                    // [0,32)
    const int m0  = (cu & 7) * 256;              // constant per CU
    const int nb  = cu >> 3;                     // [0,4): n0(i) = (4i+nb)*128

    const unsigned short* Ae = Xb + (size_t)e * TT * KP + (size_t)m0 * KP;
    const unsigned short* Ae128 = Ae + (size_t)128 * KP;
    unsigned short* He = Hb + (size_t)e * TT * DH;

    // Stage-side: chunk c of 1024 16B-chunks/half; src pos cs = c ^ ((c>>3)&7).
    const int c0 = tid, c1 = 512 + tid;
    const int cs0 = c0 ^ ((c0 >> 3) & 7), cs1 = c1 ^ ((c1 >> 3) & 7);
    const int row0 = cs0 >> 3, col0 = (cs0 & 7) * 8;
    const int row1 = cs1 >> 3, col1 = (cs1 & 7) * 8;
    const size_t loff0 = (size_t)row0 * KP + col0;
    const size_t loff1 = (size_t)row1 * KP + col1;
    const int wvoff = wave * 1024;

    // Read-side swizzled byte offsets within a 16KB half [128 rows][64 K].
    // 32x32x16 operand: row = lane&31, K-chunk (8 elems) = lane>>5.
    int ibA[2][4], ibB[4];
#pragma unroll
    for (int rg = 0; rg < 2; ++rg)
#pragma unroll
        for (int ks = 0; ks < 4; ++ks) {
            const int r = wr * 64 + rg * 32 + l31;
            ibA[rg][ks] = (r * 128 + ks * 32 + lh * 16) ^ ((r & 7) << 4);
        }
#pragma unroll
    for (int ks = 0; ks < 4; ++ks) {
        const int r = wc * 32 + l31;
        ibB[ks] = (r * 128 + ks * 32 + lh * 16) ^ ((r & 7) << 4);
    }

    f32x16 accG[4] = {}, accU[4] = {};           // 4 M-tiles each

    char* ldsb = (char*)lds;
    const char* ldsc = (const char*)lds;
    auto stageA = [&](int ro, int kk, int so) {
        gld16(Ae + (size_t)ro * KP + kk + loff0, ldsb + so + wvoff);
        gld16(Ae + (size_t)ro * KP + kk + loff1, ldsb + so + 8192 + wvoff);
    };
    auto stageW = [&](const unsigned short* p, int kk, int so) {
        gld16(p + kk + loff0, ldsb + so + wvoff);
        gld16(p + kk + loff1, ldsb + so + 8192 + wvoff);
    };
    auto w10 = [](int x) { return x >= 10 ? x - 10 : x; };

    const size_t NSTEP = (size_t)512 * KP;       // 4*128 weight rows per tile
    const unsigned short* Gc = Wgt + (size_t)e * DH * KP + (size_t)(nb * 128) * KP;
    const unsigned short* Dc = Wdt + (size_t)e * DH * KP + (size_t)(nb * 128) * KP;

    // Prologue: g0 {A0,G,D,A1} -> slots 0..3; g1 {A0,G,D} -> 4..6.
    stageA(0, 0, 0 << 14);  stageW(Gc, 0, 1 << 14);  stageW(Dc, 0, 2 << 14);  stageA(128, 0, 3 << 14);
    stageA(0, 64, 4 << 14); stageW(Gc, 64, 5 << 14); stageW(Dc, 64, 6 << 14);
    asm volatile("s_waitcnt vmcnt(6)" ::: "memory");
    asm volatile("s_barrier" ::: "memory");

    int q = 0;                                   // (4g) % 10
    for (int i = 0; i < 11; ++i) {
        const unsigned short* Gn = Gc + NSTEP;
        const unsigned short* Dn = Dc + NSTEP;
        for (int t = 0; t < 32; ++t) {
            const int g = (i << 5) + t;          // global step, [0,352)
            const int sA0 = q << 14;
            const int sG  = w10(q + 1) << 14;
            const int sD  = w10(q + 2) << 14;
            const int sA1 = w10(q + 3) << 14;
            const int stA1 = w10(q + 7) << 14;   // stale (read at g-1)
            const int stA0 = w10(q + 8) << 14;   // stale
            const int stG  = w10(q + 9) << 14;   // stale
            const int stD  = sA0;                // turnaround (read this step)

            // Early stages into stale slots.
            if (i < 10 || t + 1 < 32)
                stageA(128, ((t + 1) & 31) * 64, stA1);
            if (i < 10 || t + 2 < 32) {
                stageA(0, ((t + 2) & 31) * 64, stA0);
                stageW((t < 30) ? Gc : Gn, ((t + 2) & 31) * 64, stG);
            }

            // Reads + MFMA, compiler-scheduled (counted lgkmcnt auto-emitted).
            short8 aF[4][4], gF[4], dF[4];
#pragma unroll
            for (int ks = 0; ks < 4; ++ks) {
                aF[0][ks] = *(const short8*)(ldsc + sA0 + ibA[0][ks]);
                aF[1][ks] = *(const short8*)(ldsc + sA0 + ibA[1][ks]);
                aF[2][ks] = *(const short8*)(ldsc + sA1 + ibA[0][ks]);
                aF[3][ks] = *(const short8*)(ldsc + sA1 + ibA[1][ks]);
                gF[ks] = *(const short8*)(ldsc + sG + ibB[ks]);
                dF[ks] = *(const short8*)(ldsc + sD + ibB[ks]);
#pragma unroll
                for (int mt = 0; mt < 4; ++mt) {
                    accG[mt] = __builtin_amdgcn_mfma_f32_32x32x16_bf16(
                        aF[mt][ks], gF[ks], accG[mt], 0, 0, 0);
                    accU[mt] = __builtin_amdgcn_mfma_f32_32x32x16_bf16(
                        aF[mt][ks], dF[ks], accU[mt], 0, 0, 0);
                }
            }

            // Drain this wave's ds_reads before the turnaround-slot stage.
            asm volatile("s_waitcnt lgkmcnt(0)" ::: "memory");
            __builtin_amdgcn_sched_barrier(0);
            asm volatile("s_barrier" ::: "memory");
            if (i < 10 || t + 2 < 32)
                stageW((t < 30) ? Dc : Dn, ((t + 2) & 31) * 64, stD);
            if (g < 350)       asm volatile("s_waitcnt vmcnt(6)" ::: "memory");
            else if (g == 350) asm volatile("s_waitcnt vmcnt(0)" ::: "memory");
            asm volatile("s_barrier" ::: "memory");
            q = w10(q + 4);
        }

        // Tile epilogue: H = silu(G)*U.
        // 32x32 C/D: col = lane&31, row = (reg&3) + 8*(reg>>2) + 4*(lane>>5).
        const int n0i = (4 * i + nb) * 128;
        const int col = n0i + wc * 32 + l31;
#pragma unroll
        for (int mt = 0; mt < 4; ++mt) {
            const int row_b = m0 + (mt >> 1) * 128 + wr * 64 + (mt & 1) * 32 + 4 * lh;
#pragma unroll
            for (int j = 0; j < 16; ++j) {
                const int row = row_b + (j & 3) + 8 * (j >> 2);
                const float gv = accG[mt][j];
                const float uv = accU[mt][j];
                const float h = gv / (1.f + __expf(-gv)) * uv;
                He[(size_t)row * DH + col] = f2bf(h);
            }
        }
#pragma unroll
        for (int mt = 0; mt < 4; ++mt)
#pragma unroll
            for (int j = 0; j < 16; ++j) { accG[mt][j] = 0.f; accU[mt][j] = 0.f; }
        Gc = Gn; Dc = Dn;
    }
}

// ---------------------------------------------------------------------------
// Out-GEMM (persistent, ring-10, 32x32x16): 2 tiles of 256x256, BK=64.
// Per wave: 4 M-tiles x 2 N-tiles. Same step skeleton; turnaround = B1.
// ---------------------------------------------------------------------------
__global__ __launch_bounds__(512, 2) void gemm_out(
    const unsigned short* __restrict__ Ab,   // H [E][T][DH] bf16
    const unsigned short* __restrict__ Btb,  // WuT [E][DIN][DH] bf16
    float* __restrict__ Cf)                  // [E][T][DIN] fp32
{
    __shared__ __align__(16) unsigned short lds[81920];  // 160 KB

    const int tid  = threadIdx.x;
    const int wave = tid >> 6, lane = tid & 63;
    const int l31 = lane & 31, lh = lane >> 5;
    const int wr = wave >> 2, wc = wave & 3;     // 2M x 4N

    const int bid = blockIdx.x;                  // 256
    const int e   = bid & 7;
    const int cu  = bid >> 3;                    // [0,32)
    const int m0  = (cu & 7) * 256;
    const int nb  = cu >> 3;                     // n0(i) = (4i+nb)*256

    const unsigned short* Ae = Ab + (size_t)e * TT * DH + (size_t)m0 * DH;

    const int c0 = tid, c1 = 512 + tid;
    const int cs0 = c0 ^ ((c0 >> 3) & 7), cs1 = c1 ^ ((c1 >> 3) & 7);
    const int row0 = cs0 >> 3, col0 = (cs0 & 7) * 8;
    const int row1 = cs1 >> 3, col1 = (cs1 & 7) * 8;
    const size_t loff0 = (size_t)row0 * DH + col0;
    const size_t loff1 = (size_t)row1 * DH + col1;
    const int wvoff = wave * 1024;

    int ibA[2][4], ibB[4];
#pragma unroll
    for (int rg = 0; rg < 2; ++rg)
#pragma unroll
        for (int ks = 0; ks < 4; ++ks) {
            const int r = wr * 64 + rg * 32 + l31;
            ibA[rg][ks] = (r * 128 + ks * 32 + lh * 16) ^ ((r & 7) << 4);
        }
#pragma unroll
    for (int ks = 0; ks < 4; ++ks) {
        const int r = wc * 32 + l31;
        ibB[ks] = (r * 128 + ks * 32 + lh * 16) ^ ((r & 7) << 4);
    }

    f32x16 acc[4][2] = {};                       // M-tile x N-tile

    char* ldsb = (char*)lds;
    const char* ldsc = (const char*)lds;
    auto stageA = [&](int ro, int kk, int so) {
        gld16(Ae + (size_t)ro * DH + kk + loff0, ldsb + so + wvoff);
        gld16(Ae + (size_t)ro * DH + kk + loff1, ldsb + so + 8192 + wvoff);
    };
    auto stageB = [&](const unsigned short* base, int co, int kk, int so) {
        gld16(base + (size_t)co * DH + kk + loff0, ldsb + so + wvoff);
        gld16(base + (size_t)co * DH + kk + loff1, ldsb + so + 8192 + wvoff);
    };
    auto w10 = [](int x) { return x >= 10 ? x - 10 : x; };

    const size_t NSTEP = (size_t)1024 * DH;      // 4*256 B rows per tile
    const unsigned short* Bc = Btb + (size_t)e * DIN * DH + (size_t)(nb * 256) * DH;

    stageA(0, 0, 0 << 14); stageB(Bc, 0, 0, 1 << 14); stageB(Bc, 128, 0, 2 << 14); stageA(128, 0, 3 << 14);
    stageA(0, 64, 4 << 14); stageB(Bc, 0, 64, 5 << 14); stageB(Bc, 128, 64, 6 << 14);
    asm volatile("s_waitcnt vmcnt(6)" ::: "memory");
    asm volatile("s_barrier" ::: "memory");

    int q = 0;
    for (int i = 0; i < 2; ++i) {
        const unsigned short* Bn = Bc + NSTEP;
        for (int t = 0; t < 88; ++t) {
            const int g = i * 88 + t;            // global step, [0,176)
            const int sA0 = q << 14;
            const int sB0 = w10(q + 1) << 14;
            const int sB1 = w10(q + 2) << 14;
            const int sA1 = w10(q + 3) << 14;
            const int stA1 = w10(q + 7) << 14;
            const int stA0 = w10(q + 8) << 14;
            const int stB0 = w10(q + 9) << 14;
            const int stB1 = sA0;                // turnaround

            {
                const int t1 = t + 1;
                if (i < 1 || t1 < 88)
                    stageA(128, (t1 >= 88 ? t1 - 88 : t1) * 64, stA1);
            }
            {
                const int t2 = t + 2;
                if (i < 1 || t2 < 88) {
                    stageA(0, (t2 >= 88 ? t2 - 88 : t2) * 64, stA0);
                    stageB((t2 >= 88 ? Bn : Bc), 0, (t2 >= 88 ? t2 - 88 : t2) * 64, stB0);
                }
            }

            short8 aF[4][4], bF[2][4];
#pragma unroll
            for (int ks = 0; ks < 4; ++ks) {
                aF[0][ks] = *(const short8*)(ldsc + sA0 + ibA[0][ks]);
                aF[1][ks] = *(const short8*)(ldsc + sA0 + ibA[1][ks]);
                aF[2][ks] = *(const short8*)(ldsc + sA1 + ibA[0][ks]);
                aF[3][ks] = *(const short8*)(ldsc + sA1 + ibA[1][ks]);
                bF[0][ks] = *(const short8*)(ldsc + sB0 + ibB[ks]);
                bF[1][ks] = *(const short8*)(ldsc + sB1 + ibB[ks]);
#pragma unroll
                for (int mt = 0; mt < 4; ++mt) {
                    acc[mt][0] = __builtin_amdgcn_mfma_f32_32x32x16_bf16(
                        aF[mt][ks], bF[0][ks], acc[mt][0], 0, 0, 0);
                    acc[mt][1] = __builtin_amdgcn_mfma_f32_32x32x16_bf16(
                        aF[mt][ks], bF[1][ks], acc[mt][1], 0, 0, 0);
                }
            }

            asm volatile("s_waitcnt lgkmcnt(0)" ::: "memory");
            __builtin_amdgcn_sched_barrier(0);
            asm volatile("s_barrier" ::: "memory");
            {
                const int t2 = t + 2;
                if (i < 1 || t2 < 88)
                    stageB((t2 >= 88 ? Bn : Bc), 128, (t2 >= 88 ? t2 - 88 : t2) * 64, stB1);
            }
            if (g < 174)       asm volatile("s_waitcnt vmcnt(6)" ::: "memory");
            else if (g == 174) asm volatile("s_waitcnt vmcnt(0)" ::: "memory");
            asm volatile("s_barrier" ::: "memory");
            q = w10(q + 4);
        }

        // Tile epilogue: fp32 store, then zero acc.
        const int n0i = (4 * i + nb) * 256;
        float* Ce = Cf + (size_t)e * TT * DIN;
#pragma unroll
        for (int mt = 0; mt < 4; ++mt) {
            const int row_b = m0 + (mt >> 1) * 128 + wr * 64 + (mt & 1) * 32 + 4 * lh;
#pragma unroll
            for (int nt = 0; nt < 2; ++nt) {
                const int col = n0i + nt * 128 + wc * 32 + l31;
#pragma unroll
                for (int j = 0; j < 16; ++j) {
                    const int row = row_b + (j & 3) + 8 * (j >> 2);
                    Ce[(size_t)row * DIN + col] = acc[mt][nt][j];
                }
            }
        }
#pragma unroll
        for (int mt = 0; mt < 4; ++mt)
#pragma unroll
            for (int nt = 0; nt < 2; ++nt)
#pragma unroll
                for (int j = 0; j < 16; ++j) acc[mt][nt][j] = 0.f;
        Bc = Bn;
    }
}

// out[z][C][opitch] (bf16) = convert(in[z][R][C] (f32)). 64x64 tiles.
__global__ __launch_bounds__(256) void transpose_f32_bf16(
    const float* __restrict__ in, unsigned short* __restrict__ out,
    int R, int C, int opitch, size_t ies, size_t oes)
{
    in  += (size_t)blockIdx.z * ies;
    out += (size_t)blockIdx.z * oes;
    __shared__ unsigned short t[64][65];
    const int tid = threadIdx.x;
    const int lr = tid >> 4, lc = (tid & 15) * 4;
    const int r0 = blockIdx.y * 64, c0 = blockIdx.x * 64;
#pragma unroll
    for (int i = 0; i < 4; ++i) {
        const int row = lr + i * 16;
        const float4 v = *(const float4*)(in + (size_t)(r0 + row) * C + c0 + lc);
        t[row][lc + 0] = f2bf(v.x); t[row][lc + 1] = f2bf(v.y);
        t[row][lc + 2] = f2bf(v.z); t[row][lc + 3] = f2bf(v.w);
    }
    __syncthreads();
#pragma unroll
    for (int i = 0; i < 4; ++i) {
        const int crow = lr + i * 16;
        ushort4 wv;
        wv.x = t[lc + 0][crow]; wv.y = t[lc + 1][crow];
        wv.z = t[lc + 2][crow]; wv.w = t[lc + 3][crow];
        *(ushort4*)(out + (size_t)(c0 + crow) * opitch + r0 + lc) = wv;
    }
}

// X [rows][2048] f32 -> [rows][KP] bf16 (row-padded).
__global__ __launch_bounds__(256) void conv_pad_f32_bf16(
    const float* __restrict__ in, unsigned short* __restrict__ out, int n8)
{
    int i = blockIdx.x * 256 + threadIdx.x;
    const int stride = gridDim.x * 256;
    for (; i < n8; i += stride) {
        const int row = i >> 8;                  // 256 chunks of 8 per row
        const int col = (i & 255) * 8;
        const float4 v0 = *(const float4*)(in + (size_t)row * DIN + col);
        const float4 v1 = *(const float4*)(in + (size_t)row * DIN + col + 4);
        ushort4 a, b;
        a.x = f2bf(v0.x); a.y = f2bf(v0.y); a.z = f2bf(v0.z); a.w = f2bf(v0.w);
        b.x = f2bf(v1.x); b.y = f2bf(v1.y); b.z = f2bf(v1.z); b.w = f2bf(v1.w);
        *(ushort4*)(out + (size_t)row * KP + col) = a;
        *(ushort4*)(out + (size_t)row * KP + col + 4) = b;
    }
}

extern "C" void kernel_launch(void* const* d_in, const int* in_sizes, int n_in,
                              void* d_out, int out_size, void* d_ws, size_t ws_size,
                              hipStream_t stream)
{
    const float* x  = (const float*)d_in[0];  // [E,T,DIN]
    const float* wg = (const float*)d_in[1];  // [E,DIN,DH]
    const float* wd = (const float*)d_in[2];  // [E,DIN,DH]
    const float* wu = (const float*)d_in[3];  // [E,DH,DIN]
    float* out = (float*)d_out;               // [E,T,DIN] fp32

    const size_t XSZ = (size_t)TT * KP;       // per-expert X elems (padded)
    const size_t WPSZ = (size_t)DH * KP;      // per-expert padded weight elems
    const size_t WSZ = (size_t)DIN * DH;      // per-expert WuT elems (unpadded)
    unsigned short* xb  = (unsigned short*)d_ws;      // [E] X bf16 padded  68 MB
    unsigned short* wgt = xb  + (size_t)NEXP * XSZ;   // [E] WgT / WuT     188 MB
    unsigned short* wdt = wgt + (size_t)NEXP * WPSZ;  // [E] WdT           188 MB
    unsigned short* hb  = wdt + (size_t)NEXP * WPSZ;  // [E] H             185 MB
    // total ws: ~628 MB

    // X -> bf16 padded rows
    conv_pad_f32_bf16<<<4096, 256, 0, stream>>>(x, xb, NEXP * TT * (DIN / 8));
    // WgT, WdT: [E][DH][KP] K-major padded
    transpose_f32_bf16<<<dim3(DH / 64, DIN / 64, NEXP), 256, 0, stream>>>(
        wg, wgt, DIN, DH, KP, WSZ, WPSZ);
    transpose_f32_bf16<<<dim3(DH / 64, DIN / 64, NEXP), 256, 0, stream>>>(
        wd, wdt, DIN, DH, KP, WSZ, WPSZ);
    // H = silu(X*Wg) * (X*Wd)   [E][T][DH]  — persistent fused dual-acc GEMM
    gemm_gu<<<256, 512, 0, stream>>>(xb, wgt, wdt, hb);
    // WuT: [E][DIN][DH] K-major, stride 5632 non-pow2 (reuse wgt region)
    transpose_f32_bf16<<<dim3(DIN / 64, DH / 64, NEXP), 256, 0, stream>>>(
        wu, wgt, DH, DIN, DH, WSZ, WSZ);
    // Out = H * Wu   [E][T][DIN] fp32  — persistent
    gemm_out<<<256, 512, 0, stream>>>(hb, wgt, out);
}